// Round 1
// baseline (287.555 us; speedup 1.0000x reference)
//
#include <hip/hip_runtime.h>
#include <math.h>

static constexpr int BLK = 256;

__device__ __forceinline__ unsigned f2u(float f) { return __float_as_uint(f); }

// Prep: pack (x,y,z,0.5*|p|^2) for both point sets, init result sentinels, zero out.
__global__ void prep_kernel(const float* __restrict__ P, const float* __restrict__ Ps,
                            float4* __restrict__ pp, float4* __restrict__ psp,
                            unsigned long long* __restrict__ o2s, unsigned* __restrict__ s2o,
                            float* __restrict__ out, int N, int M) {
    int i = blockIdx.x * blockDim.x + threadIdx.x;
    if (i < N) {
        float x = P[3 * i], y = P[3 * i + 1], z = P[3 * i + 2];
        pp[i] = make_float4(x, y, z, 0.5f * (x * x + y * y + z * z));
        o2s[i] = ~0ull;
    }
    if (i < M) {
        float x = Ps[3 * i], y = Ps[3 * i + 1], z = Ps[3 * i + 2];
        psp[i] = make_float4(x, y, z, 0.5f * (x * x + y * y + z * z));
        s2o[i] = 0xFFFFFFFFu;
    }
    if (i == 0) out[0] = 0.0f;
}

// original -> sampled: per P point, min + argmin over a tile of Ps points.
// min over d2 == min over m = 0.5|q|^2 - p.q  (d2 = 2*(0.5|p|^2 + m), >= 0)
__global__ void o2s_kernel(const float4* __restrict__ pp, const float4* __restrict__ psp,
                           unsigned long long* __restrict__ o2s, int N, int M, int jTile) {
    int i = blockIdx.x * BLK + threadIdx.x;
    if (i >= N) return;
    float4 p = pp[i];
    float npx = -p.x, npy = -p.y, npz = -p.z;
    int j0 = blockIdx.y * jTile;
    int j1 = min(j0 + jTile, M);
    float mmin = __builtin_inff();
    int mj = j0;
#pragma unroll 4
    for (int j = j0; j < j1; ++j) {
        float4 q = psp[j];  // wave-uniform address -> scalar load expected
        float m = fmaf(q.x, npx, fmaf(q.y, npy, fmaf(q.z, npz, q.w)));
        if (m < mmin) { mmin = m; mj = j; }
    }
    float d2 = fmaxf(2.0f * (p.w + mmin), 0.0f);
    unsigned long long key = ((unsigned long long)f2u(d2) << 32) | (unsigned)mj;
    atomicMin(&o2s[i], key);
}

// sampled -> original: per Ps point, min only over a tile of P points.
__global__ void s2o_kernel(const float4* __restrict__ psp, const float4* __restrict__ pp,
                           unsigned* __restrict__ s2o, int M, int N, int iTile) {
    int j = blockIdx.x * BLK + threadIdx.x;
    if (j >= M) return;
    float4 q = psp[j];
    float nqx = -q.x, nqy = -q.y, nqz = -q.z;
    int i0 = blockIdx.y * iTile;
    int i1 = min(i0 + iTile, N);
    float mmin = __builtin_inff();
#pragma unroll 4
    for (int i = i0; i < i1; ++i) {
        float4 p = pp[i];  // wave-uniform address -> scalar load expected
        float m = fmaf(p.x, nqx, fmaf(p.y, nqy, fmaf(p.z, nqz, p.w)));
        mmin = fminf(mmin, m);
    }
    float d2 = fmaxf(2.0f * (q.w + mmin), 0.0f);
    atomicMin(&s2o[j], f2u(d2));
}

// Weighted sums of both directions, block-reduced, one atomicAdd per block.
__global__ void finish_kernel(const unsigned* __restrict__ s2o,
                              const unsigned long long* __restrict__ o2s,
                              const float* __restrict__ prob,
                              float* __restrict__ out, int N, int M) {
    int t = blockIdx.x * BLK + threadIdx.x;
    float acc = 0.0f;
    if (t < M) {
        acc = sqrtf(__uint_as_float(s2o[t])) * prob[t];
    } else if (t < M + N) {
        unsigned long long key = o2s[t - M];
        float d2 = __uint_as_float((unsigned)(key >> 32));
        unsigned jj = (unsigned)(key & 0xFFFFFFFFu);
        acc = sqrtf(d2) * prob[jj];
    }
#pragma unroll
    for (int off = 32; off > 0; off >>= 1) acc += __shfl_down(acc, off, 64);
    __shared__ float wsum[BLK / 64];
    int lane = threadIdx.x & 63, wave = threadIdx.x >> 6;
    if (lane == 0) wsum[wave] = acc;
    __syncthreads();
    if (threadIdx.x == 0) {
        float s = 0.0f;
#pragma unroll
        for (int w = 0; w < BLK / 64; ++w) s += wsum[w];
        atomicAdd(out, s);
    }
}

extern "C" void kernel_launch(void* const* d_in, const int* in_sizes, int n_in,
                              void* d_out, int out_size, void* d_ws, size_t ws_size,
                              hipStream_t stream) {
    const float* P = (const float*)d_in[0];
    const float* Ps = (const float*)d_in[1];
    const float* prob = (const float*)d_in[2];
    int N = in_sizes[0] / 3;  // 32768
    int M = in_sizes[1] / 3;  // 8192

    char* ws = (char*)d_ws;
    float4* pp = (float4*)ws;                                       // N * 16 B
    float4* psp = (float4*)(ws + (size_t)N * 16);                   // M * 16 B
    unsigned long long* o2s =
        (unsigned long long*)(ws + (size_t)N * 16 + (size_t)M * 16); // N * 8 B
    unsigned* s2o =
        (unsigned*)(ws + (size_t)N * 16 + (size_t)M * 16 + (size_t)N * 8); // M * 4 B
    float* out = (float*)d_out;

    int prepBlocks = (max(N, M) + BLK - 1) / BLK;
    prep_kernel<<<prepBlocks, BLK, 0, stream>>>(P, Ps, pp, psp, o2s, s2o, out, N, M);

    // o2s: 128 x 8 = 1024 blocks, each scans M/8 = 1024 sampled points
    int jTiles = 8;
    int jTile = (M + jTiles - 1) / jTiles;
    dim3 g1((N + BLK - 1) / BLK, jTiles);
    o2s_kernel<<<g1, BLK, 0, stream>>>(pp, psp, o2s, N, M, jTile);

    // s2o: 32 x 16 = 512 blocks, each scans N/16 = 2048 original points
    int iTiles = 16;
    int iTile = (N + iTiles - 1) / iTiles;
    dim3 g2((M + BLK - 1) / BLK, iTiles);
    s2o_kernel<<<g2, BLK, 0, stream>>>(psp, pp, s2o, M, N, iTile);

    finish_kernel<<<(N + M + BLK - 1) / BLK, BLK, 0, stream>>>(s2o, o2s, prob, out, N, M);
}

// Round 2
// 117.629 us; speedup vs baseline: 2.4446x; 2.4446x over previous
//
#include <hip/hip_runtime.h>
#include <math.h>

static constexpr int BLK = 256;
static constexpr int R = 4;      // queries per thread
static constexpr int TILE = 256; // scan points staged in LDS per block

__device__ __forceinline__ unsigned f2u(float f) { return __float_as_uint(f); }

// Prep: pack (x,y,z,0.5*|p|^2) for both point sets, init result sentinels, zero out.
__global__ void prep_kernel(const float* __restrict__ P, const float* __restrict__ Ps,
                            float4* __restrict__ pp, float4* __restrict__ psp,
                            unsigned long long* __restrict__ o2s, unsigned* __restrict__ s2o,
                            float* __restrict__ out, int N, int M) {
    int i = blockIdx.x * blockDim.x + threadIdx.x;
    if (i < N) {
        float x = P[3 * i], y = P[3 * i + 1], z = P[3 * i + 2];
        pp[i] = make_float4(x, y, z, 0.5f * (x * x + y * y + z * z));
        o2s[i] = ~0ull;
    }
    if (i < M) {
        float x = Ps[3 * i], y = Ps[3 * i + 1], z = Ps[3 * i + 2];
        psp[i] = make_float4(x, y, z, 0.5f * (x * x + y * y + z * z));
        s2o[i] = 0xFFFFFFFFu;
    }
    if (i == 0) out[0] = 0.0f;
}

// original -> sampled: min+argmin. min over d2 == min over m = 0.5|q|^2 - p.q
__global__ void __launch_bounds__(BLK) o2s_kernel(const float4* __restrict__ pp,
                                                  const float4* __restrict__ psp,
                                                  unsigned long long* __restrict__ o2s,
                                                  int N, int M) {
    __shared__ float4 tile[TILE];
    int ibase = blockIdx.x * (BLK * R) + threadIdx.x;
    int j0 = blockIdx.y * TILE;
    float4 p[R];
    float mmin[R];
    int mj[R];
#pragma unroll
    for (int r = 0; r < R; ++r) {
        int i = ibase + r * BLK;
        p[r] = (i < N) ? pp[i] : make_float4(0.f, 0.f, 0.f, 0.f);
        mmin[r] = __builtin_inff();
        mj[r] = j0;
    }
    int idx = j0 + threadIdx.x;
    tile[threadIdx.x] =
        (idx < M) ? psp[idx] : make_float4(0.f, 0.f, 0.f, __builtin_inff());
    __syncthreads();
#pragma unroll 4
    for (int ii = 0; ii < TILE; ++ii) {
        float4 q = tile[ii];
#pragma unroll
        for (int r = 0; r < R; ++r) {
            float m = fmaf(q.x, -p[r].x, fmaf(q.y, -p[r].y, fmaf(q.z, -p[r].z, q.w)));
            if (m < mmin[r]) { mmin[r] = m; mj[r] = j0 + ii; }
        }
    }
#pragma unroll
    for (int r = 0; r < R; ++r) {
        int i = ibase + r * BLK;
        if (i < N) {
            float d2 = fmaxf(2.0f * (p[r].w + mmin[r]), 0.0f);
            unsigned long long key =
                ((unsigned long long)f2u(d2) << 32) | (unsigned)mj[r];
            atomicMin(&o2s[i], key);
        }
    }
}

// sampled -> original: min only.
__global__ void __launch_bounds__(BLK) s2o_kernel(const float4* __restrict__ psp,
                                                  const float4* __restrict__ pp,
                                                  unsigned* __restrict__ s2o,
                                                  int M, int N) {
    __shared__ float4 tile[TILE];
    int jbase = blockIdx.x * (BLK * R) + threadIdx.x;
    int i0 = blockIdx.y * TILE;
    float4 q[R];
    float mmin[R];
#pragma unroll
    for (int r = 0; r < R; ++r) {
        int j = jbase + r * BLK;
        q[r] = (j < M) ? psp[j] : make_float4(0.f, 0.f, 0.f, 0.f);
        mmin[r] = __builtin_inff();
    }
    int idx = i0 + threadIdx.x;
    tile[threadIdx.x] =
        (idx < N) ? pp[idx] : make_float4(0.f, 0.f, 0.f, __builtin_inff());
    __syncthreads();
#pragma unroll 4
    for (int ii = 0; ii < TILE; ++ii) {
        float4 p = tile[ii];
#pragma unroll
        for (int r = 0; r < R; ++r) {
            float m = fmaf(p.x, -q[r].x, fmaf(p.y, -q[r].y, fmaf(p.z, -q[r].z, p.w)));
            mmin[r] = fminf(mmin[r], m);
        }
    }
#pragma unroll
    for (int r = 0; r < R; ++r) {
        int j = jbase + r * BLK;
        if (j < M) {
            float d2 = fmaxf(2.0f * (q[r].w + mmin[r]), 0.0f);
            atomicMin(&s2o[j], f2u(d2));
        }
    }
}

// Weighted sums of both directions, block-reduced, one atomicAdd per block.
__global__ void finish_kernel(const unsigned* __restrict__ s2o,
                              const unsigned long long* __restrict__ o2s,
                              const float* __restrict__ prob,
                              float* __restrict__ out, int N, int M) {
    int t = blockIdx.x * BLK + threadIdx.x;
    float acc = 0.0f;
    if (t < M) {
        acc = sqrtf(__uint_as_float(s2o[t])) * prob[t];
    } else if (t < M + N) {
        unsigned long long key = o2s[t - M];
        float d2 = __uint_as_float((unsigned)(key >> 32));
        unsigned jj = (unsigned)(key & 0xFFFFFFFFu);
        acc = sqrtf(d2) * prob[jj];
    }
#pragma unroll
    for (int off = 32; off > 0; off >>= 1) acc += __shfl_down(acc, off, 64);
    __shared__ float wsum[BLK / 64];
    int lane = threadIdx.x & 63, wave = threadIdx.x >> 6;
    if (lane == 0) wsum[wave] = acc;
    __syncthreads();
    if (threadIdx.x == 0) {
        float s = 0.0f;
#pragma unroll
        for (int w = 0; w < BLK / 64; ++w) s += wsum[w];
        atomicAdd(out, s);
    }
}

extern "C" void kernel_launch(void* const* d_in, const int* in_sizes, int n_in,
                              void* d_out, int out_size, void* d_ws, size_t ws_size,
                              hipStream_t stream) {
    const float* P = (const float*)d_in[0];
    const float* Ps = (const float*)d_in[1];
    const float* prob = (const float*)d_in[2];
    int N = in_sizes[0] / 3;  // 32768
    int M = in_sizes[1] / 3;  // 8192

    char* ws = (char*)d_ws;
    float4* pp = (float4*)ws;                                        // N * 16 B
    float4* psp = (float4*)(ws + (size_t)N * 16);                    // M * 16 B
    unsigned long long* o2s =
        (unsigned long long*)(ws + (size_t)N * 16 + (size_t)M * 16); // N * 8 B
    unsigned* s2o =
        (unsigned*)(ws + (size_t)N * 16 + (size_t)M * 16 + (size_t)N * 8); // M * 4 B
    float* out = (float*)d_out;

    int prepBlocks = (max(N, M) + BLK - 1) / BLK;
    prep_kernel<<<prepBlocks, BLK, 0, stream>>>(P, Ps, pp, psp, o2s, s2o, out, N, M);

    // o2s: x = N/(BLK*R) = 32, y = M/TILE = 32 -> 1024 blocks
    dim3 g1((N + BLK * R - 1) / (BLK * R), (M + TILE - 1) / TILE);
    o2s_kernel<<<g1, BLK, 0, stream>>>(pp, psp, o2s, N, M);

    // s2o: x = M/(BLK*R) = 8, y = N/TILE = 128 -> 1024 blocks
    dim3 g2((M + BLK * R - 1) / (BLK * R), (N + TILE - 1) / TILE);
    s2o_kernel<<<g2, BLK, 0, stream>>>(psp, pp, s2o, M, N);

    finish_kernel<<<(N + M + BLK - 1) / BLK, BLK, 0, stream>>>(s2o, o2s, prob, out, N, M);
}

// Round 3
// 111.368 us; speedup vs baseline: 2.5820x; 1.0562x over previous
//
#include <hip/hip_runtime.h>
#include <math.h>

static constexpr int BLK = 256;
static constexpr int R = 8;      // queries per thread
static constexpr int TILE = 256; // scan points staged in LDS per block

__device__ __forceinline__ unsigned f2u(float f) { return __float_as_uint(f); }

// Prep: pack (x,y,z,0.5*|p|^2) for both point sets, init result sentinels, zero out.
__global__ void prep_kernel(const float* __restrict__ P, const float* __restrict__ Ps,
                            float4* __restrict__ pp, float4* __restrict__ psp,
                            unsigned long long* __restrict__ o2s, unsigned* __restrict__ s2o,
                            float* __restrict__ out, int N, int M) {
    int i = blockIdx.x * blockDim.x + threadIdx.x;
    if (i < N) {
        float x = P[3 * i], y = P[3 * i + 1], z = P[3 * i + 2];
        pp[i] = make_float4(x, y, z, 0.5f * (x * x + y * y + z * z));
        o2s[i] = ~0ull;
    }
    if (i < M) {
        float x = Ps[3 * i], y = Ps[3 * i + 1], z = Ps[3 * i + 2];
        psp[i] = make_float4(x, y, z, 0.5f * (x * x + y * y + z * z));
        s2o[i] = 0xFFFFFFFFu;
    }
    if (i == 0) out[0] = 0.0f;
}

// Fused: blockIdx.x < o2sBlocks -> o2s (min+argmin), else -> s2o (min only).
// min over d2 == min over m = 0.5|scan|^2 - qry.scan ; d2 = 2*(0.5|qry|^2 + m)
__global__ void __launch_bounds__(BLK) main_kernel(
    const float4* __restrict__ pp, const float4* __restrict__ psp,
    unsigned long long* __restrict__ o2s, unsigned* __restrict__ s2o,
    int N, int M, int o2sX, int o2sBlocks, int s2oX) {
    __shared__ float4 tile[TILE];
    int bx = blockIdx.x;

    if (bx < o2sBlocks) {
        // ---- original -> sampled: queries = pp (N), scan = psp (M) ----
        int ix = bx % o2sX, iy = bx / o2sX;
        int ibase = ix * (BLK * R) + threadIdx.x;
        int j0 = iy * TILE;
        float4 p[R];
        float mmin[R];
        int mj[R];
#pragma unroll
        for (int r = 0; r < R; ++r) {
            int i = ibase + r * BLK;
            float4 t = (i < N) ? pp[i] : make_float4(0.f, 0.f, 0.f, 0.f);
            p[r] = make_float4(-t.x, -t.y, -t.z, t.w);
            mmin[r] = __builtin_inff();
            mj[r] = j0;
        }
        int idx = j0 + threadIdx.x;
        tile[threadIdx.x] =
            (idx < M) ? psp[idx] : make_float4(0.f, 0.f, 0.f, __builtin_inff());
        __syncthreads();
#pragma unroll 4
        for (int ii = 0; ii < TILE; ++ii) {
            float4 q = tile[ii];
#pragma unroll
            for (int r = 0; r < R; ++r) {
                float m = fmaf(q.x, p[r].x, fmaf(q.y, p[r].y, fmaf(q.z, p[r].z, q.w)));
                if (m < mmin[r]) { mmin[r] = m; mj[r] = j0 + ii; }
            }
        }
#pragma unroll
        for (int r = 0; r < R; ++r) {
            int i = ibase + r * BLK;
            if (i < N) {
                float d2 = fmaxf(2.0f * (p[r].w + mmin[r]), 0.0f);
                unsigned long long key =
                    ((unsigned long long)f2u(d2) << 32) | (unsigned)mj[r];
                atomicMin(&o2s[i], key);
            }
        }
    } else {
        // ---- sampled -> original: queries = psp (M), scan = pp (N) ----
        int b = bx - o2sBlocks;
        int ix = b % s2oX, iy = b / s2oX;
        int jbase = ix * (BLK * R) + threadIdx.x;
        int i0 = iy * TILE;
        float4 q[R];
        float mmin[R];
#pragma unroll
        for (int r = 0; r < R; ++r) {
            int j = jbase + r * BLK;
            float4 t = (j < M) ? psp[j] : make_float4(0.f, 0.f, 0.f, 0.f);
            q[r] = make_float4(-t.x, -t.y, -t.z, t.w);
            mmin[r] = __builtin_inff();
        }
        int idx = i0 + threadIdx.x;
        tile[threadIdx.x] =
            (idx < N) ? pp[idx] : make_float4(0.f, 0.f, 0.f, __builtin_inff());
        __syncthreads();
#pragma unroll 4
        for (int ii = 0; ii < TILE; ++ii) {
            float4 p = tile[ii];
#pragma unroll
            for (int r = 0; r < R; ++r) {
                float m = fmaf(p.x, q[r].x, fmaf(p.y, q[r].y, fmaf(p.z, q[r].z, p.w)));
                mmin[r] = fminf(mmin[r], m);
            }
        }
#pragma unroll
        for (int r = 0; r < R; ++r) {
            int j = jbase + r * BLK;
            if (j < M) {
                float d2 = fmaxf(2.0f * (q[r].w + mmin[r]), 0.0f);
                atomicMin(&s2o[j], f2u(d2));
            }
        }
    }
}

// Weighted sums of both directions, block-reduced, one atomicAdd per block.
__global__ void finish_kernel(const unsigned* __restrict__ s2o,
                              const unsigned long long* __restrict__ o2s,
                              const float* __restrict__ prob,
                              float* __restrict__ out, int N, int M) {
    int t = blockIdx.x * BLK + threadIdx.x;
    float acc = 0.0f;
    if (t < M) {
        acc = sqrtf(__uint_as_float(s2o[t])) * prob[t];
    } else if (t < M + N) {
        unsigned long long key = o2s[t - M];
        float d2 = __uint_as_float((unsigned)(key >> 32));
        unsigned jj = (unsigned)(key & 0xFFFFFFFFu);
        acc = sqrtf(d2) * prob[jj];
    }
#pragma unroll
    for (int off = 32; off > 0; off >>= 1) acc += __shfl_down(acc, off, 64);
    __shared__ float wsum[BLK / 64];
    int lane = threadIdx.x & 63, wave = threadIdx.x >> 6;
    if (lane == 0) wsum[wave] = acc;
    __syncthreads();
    if (threadIdx.x == 0) {
        float s = 0.0f;
#pragma unroll
        for (int w = 0; w < BLK / 64; ++w) s += wsum[w];
        atomicAdd(out, s);
    }
}

extern "C" void kernel_launch(void* const* d_in, const int* in_sizes, int n_in,
                              void* d_out, int out_size, void* d_ws, size_t ws_size,
                              hipStream_t stream) {
    const float* P = (const float*)d_in[0];
    const float* Ps = (const float*)d_in[1];
    const float* prob = (const float*)d_in[2];
    int N = in_sizes[0] / 3;  // 32768
    int M = in_sizes[1] / 3;  // 8192

    char* ws = (char*)d_ws;
    float4* pp = (float4*)ws;                                        // N * 16 B
    float4* psp = (float4*)(ws + (size_t)N * 16);                    // M * 16 B
    unsigned long long* o2s =
        (unsigned long long*)(ws + (size_t)N * 16 + (size_t)M * 16); // N * 8 B
    unsigned* s2o =
        (unsigned*)(ws + (size_t)N * 16 + (size_t)M * 16 + (size_t)N * 8); // M * 4 B
    float* out = (float*)d_out;

    int prepBlocks = (max(N, M) + BLK - 1) / BLK;
    prep_kernel<<<prepBlocks, BLK, 0, stream>>>(P, Ps, pp, psp, o2s, s2o, out, N, M);

    // o2s: x = 32768/2048 = 16, y = 8192/256 = 32  -> 512 blocks
    // s2o: x =  8192/2048 =  4, y = 32768/256 = 128 -> 512 blocks
    int o2sX = (N + BLK * R - 1) / (BLK * R);
    int o2sY = (M + TILE - 1) / TILE;
    int s2oX = (M + BLK * R - 1) / (BLK * R);
    int s2oY = (N + TILE - 1) / TILE;
    int o2sBlocks = o2sX * o2sY;
    int total = o2sBlocks + s2oX * s2oY;
    main_kernel<<<total, BLK, 0, stream>>>(pp, psp, o2s, s2o, N, M, o2sX, o2sBlocks, s2oX);

    finish_kernel<<<(N + M + BLK - 1) / BLK, BLK, 0, stream>>>(s2o, o2s, prob, out, N, M);
}